// Round 4
// baseline (46.028 us; speedup 1.0000x reference)
//
#include <hip/hip_runtime.h>

// Elementwise: y = x*w + b (w,b broadcast over batch); out = y if 0 < y <= 1 else 0.
// x: [8192, 4096] f32, w: [4096] f32, b: [4096] f32, out: [8192, 4096] f32.
//
// Round-3 insight: FETCH_SIZE was only ~64 MB (not 128 MB) — x is partially
// L3-resident across replays, but out's write-allocate evicts half of it
// (x + out = 256 MB = L3 size). This round: NONTEMPORAL STORE ONLY (plain
// load) so out bypasses the cache and x stays fully L3-resident.
// Round-2 (NT load + NT store) regressed; hypothesis: the NT LOAD was the
// culprit (bypassed L3 for x -> +64 MB HBM fetch ~= the +5.4 us seen).
//
//  - grid-stride (2048 blocks x 256 thr = 524288 lanes) in float4 units is a
//    multiple of 1024 (= 4096 floats / 4), so each thread's w/b column is
//    LOOP-INVARIANT -> w/b loads hoisted out of the loop.
//  - n4 (8388608) = 16 x lane count: exactly 8 unrolled-x2 iterations, no tail.

typedef float f32x4 __attribute__((ext_vector_type(4)));

__device__ __forceinline__ f32x4 capped(f32x4 y) {
    f32x4 r;
    r.x = (y.x > 0.0f && y.x <= 1.0f) ? y.x : 0.0f;
    r.y = (y.y > 0.0f && y.y <= 1.0f) ? y.y : 0.0f;
    r.z = (y.z > 0.0f && y.z <= 1.0f) ? y.z : 0.0f;
    r.w = (y.w > 0.0f && y.w <= 1.0f) ? y.w : 0.0f;
    return r;
}

__global__ void __launch_bounds__(256)
capped_relu_kernel(const f32x4* __restrict__ x4,
                   const float* __restrict__ w,
                   const float* __restrict__ b,
                   f32x4* __restrict__ out4,
                   long n4) {
    const long stride = (long)gridDim.x * blockDim.x;   // multiple of 1024 by construction
    long i = (long)blockIdx.x * blockDim.x + threadIdx.x;
    if (i >= n4) return;

    // Column of this thread's float4 — invariant across grid-stride iterations
    // because stride*4 % 4096 == 0.
    const int c = (int)((i << 2) & 4095);
    const f32x4 wv = *reinterpret_cast<const f32x4*>(&w[c]);
    const f32x4 bv = *reinterpret_cast<const f32x4*>(&b[c]);

    for (; i + stride < n4; i += 2 * stride) {
        f32x4 v0 = x4[i];                 // plain load: keep x in L3
        f32x4 v1 = x4[i + stride];
        f32x4 r0 = capped(v0 * wv + bv);
        f32x4 r1 = capped(v1 * wv + bv);
        __builtin_nontemporal_store(r0, &out4[i]);          // NT store: don't evict x
        __builtin_nontemporal_store(r1, &out4[i + stride]);
    }
    if (i < n4) {
        __builtin_nontemporal_store(capped(x4[i] * wv + bv), &out4[i]);
    }
}

extern "C" void kernel_launch(void* const* d_in, const int* in_sizes, int n_in,
                              void* d_out, int out_size, void* d_ws, size_t ws_size,
                              hipStream_t stream) {
    const float* x = (const float*)d_in[0];
    const float* w = (const float*)d_in[1];
    const float* b = (const float*)d_in[2];
    float* out = (float*)d_out;

    const long n  = (long)out_size;        // 8192 * 4096
    const long n4 = n >> 2;                // float4 count (n is a multiple of 4)

    const int block = 256;
    long blocks_needed = (n4 + block - 1) / block;
    int grid = (int)((blocks_needed < 2048) ? blocks_needed : 2048);

    capped_relu_kernel<<<grid, block, 0, stream>>>(
        (const f32x4*)x, w, b, (f32x4*)out, n4);
}

// Round 5
// 42.008 us; speedup vs baseline: 1.0957x; 1.0957x over previous
//
#include <hip/hip_runtime.h>

// Elementwise: y = x*w + b (w,b broadcast over batch); out = y if 0 < y <= 1 else 0.
// x: [8192, 4096] f32, w: [4096] f32, b: [4096] f32, out: [8192, 4096] f32.
//
// Roofline: 268.4 MB logical read+write; m13 float4-copy ceiling = 6.29 TB/s
// -> 42.7 us floor. Round-1 grid-stride kernel = 45.4 us (94% of floor).
//
// Lessons so far:
//  - R2: NT load+store REGRESSED (+5.4 us) — NT load bypasses L3 for x.
//  - R4: NT store alone is neutral and does NOT reduce FETCH_SIZE — gfx950's
//    nt flag doesn't avoid the write-allocate eviction of x from L3. Reverted.
//  - R3: 2x unroll neutral — MLP not the limiter.
//
// This round: flat one-thread-per-float4 (grid 32768 x 256), zero loop
// control — exactly the structure of the 6.29 TB/s copy ubench. If neutral,
// we are at the mixed-stream roofline.

typedef float f32x4 __attribute__((ext_vector_type(4)));

__global__ void __launch_bounds__(256)
capped_relu_kernel(const f32x4* __restrict__ x4,
                   const float* __restrict__ w,
                   const float* __restrict__ b,
                   f32x4* __restrict__ out4,
                   long n4) {
    const long i = (long)blockIdx.x * blockDim.x + threadIdx.x;
    if (i >= n4) return;

    const int c = (int)((i << 2) & 4095);   // column of this float4
    const f32x4 wv = *reinterpret_cast<const f32x4*>(&w[c]);  // L1-resident (16 KB)
    const f32x4 bv = *reinterpret_cast<const f32x4*>(&b[c]);

    f32x4 y = x4[i] * wv + bv;
    f32x4 r;
    r.x = (y.x > 0.0f && y.x <= 1.0f) ? y.x : 0.0f;
    r.y = (y.y > 0.0f && y.y <= 1.0f) ? y.y : 0.0f;
    r.z = (y.z > 0.0f && y.z <= 1.0f) ? y.z : 0.0f;
    r.w = (y.w > 0.0f && y.w <= 1.0f) ? y.w : 0.0f;
    out4[i] = r;
}

extern "C" void kernel_launch(void* const* d_in, const int* in_sizes, int n_in,
                              void* d_out, int out_size, void* d_ws, size_t ws_size,
                              hipStream_t stream) {
    const float* x = (const float*)d_in[0];
    const float* w = (const float*)d_in[1];
    const float* b = (const float*)d_in[2];
    float* out = (float*)d_out;

    const long n  = (long)out_size;        // 8192 * 4096
    const long n4 = n >> 2;                // float4 count (n is a multiple of 4)

    const int block = 256;
    const long grid = (n4 + block - 1) / block;   // 32768 blocks, one float4/thread

    capped_relu_kernel<<<(int)grid, block, 0, stream>>>(
        (const f32x4*)x, w, b, (f32x4*)out, n4);
}